// Round 17
// baseline (403.289 us; speedup 1.0000x reference)
//
#include <hip/hip_runtime.h>
#include <cstdint>
#include <cstddef>
#include <cmath>

typedef unsigned long long u64;
typedef __attribute__((ext_vector_type(8))) short bf16x8;   // 8 bf16 in 4 VGPRs
typedef __attribute__((ext_vector_type(4))) float f32x4;

static constexpr int S_    = 2048;
static constexpr int H_    = 2048;
static constexpr int TOPKC = 512;

#define SCALE_ATTN 0.07216878364870323f   // (192)^-0.5
#define ISCALE_ID  0.08838834764831845f   // (128)^-0.5
#define EPS_F 1e-6f

__device__ inline unsigned short f2b(float f) {
  unsigned u = __float_as_uint(f);
  return (unsigned short)((u + 0x7FFFu + ((u >> 16) & 1u)) >> 16);
}
__device__ inline float b2f(unsigned short b) {
  return __uint_as_float(((unsigned)b) << 16);
}
// async global->LDS, 16B per lane; LDS dest = wave-uniform base + lane*16, global src per-lane
__device__ inline void gload16(const unsigned short* g, unsigned short* l) {
  __builtin_amdgcn_global_load_lds((const __attribute__((address_space(1))) void*)g,
                                   (__attribute__((address_space(3))) void*)l, 16, 0, 0);
}

// ================= bf16 MFMA GEMM: C[M,N] = A[M,K] @ Bt[N,K]^T (XCD-swizzled grid) =================
// MODE: 1 = bf16 out, 2 = bf16 out + fused RoPE on cols>=3072 (qi, head=128, first 64)
template<int MODE>
__global__ __launch_bounds__(256) void k_gemm_bf16(
    const unsigned short* __restrict__ A, int lda,
    const unsigned short* __restrict__ Bt, int K,
    void* __restrict__ C, int ldc, int N,
    const float* __restrict__ cosb, const float* __restrict__ sinb) {
  __shared__ unsigned short As[128 * 64];
  __shared__ unsigned short Bs[128 * 64];
  // XCD-aware bijective remap (m204)
  int nwg = gridDim.x * gridDim.y;
  int orig = blockIdx.y * gridDim.x + blockIdx.x;
  int q = nwg >> 3, r = nwg & 7;
  int xcd = orig & 7, sub = orig >> 3;
  int wgid = (xcd < r ? xcd * (q + 1) : r * (q + 1) + (xcd - r) * q) + sub;
  int by = wgid / gridDim.x, bx = wgid - by * gridDim.x;
  const int bm = by * 128, bn = bx * 128;
  const int tid = threadIdx.x;
  const int lane = tid & 63, w = tid >> 6;
  const int wm = w >> 1, wn = w & 1;
  const int l15 = lane & 15, quarter = lane >> 4;
  const int srow = (lane >> 3), scol = (lane & 7) * 8;

  f32x4 acc[4][4];
#pragma unroll
  for (int i = 0; i < 4; i++)
#pragma unroll
    for (int j = 0; j < 4; j++) acc[i][j] = (f32x4){0.f, 0.f, 0.f, 0.f};

  for (int k0 = 0; k0 < K; k0 += 64) {
    __syncthreads();
#pragma unroll
    for (int i = 0; i < 4; i++) {
      int r0 = w * 32 + i * 8;
      gload16(A  + (size_t)(bm + r0 + srow) * lda + k0 + scol, &As[r0 * 64]);
      gload16(Bt + (size_t)(bn + r0 + srow) * K   + k0 + scol, &Bs[r0 * 64]);
    }
    __syncthreads();
#pragma unroll
    for (int kc = 0; kc < 2; kc++) {
      bf16x8 af[4], bfr[4];
#pragma unroll
      for (int mf = 0; mf < 4; mf++)
        af[mf] = *(const bf16x8*)(As + (wm * 64 + mf * 16 + l15) * 64 + kc * 32 + quarter * 8);
#pragma unroll
      for (int nf = 0; nf < 4; nf++)
        bfr[nf] = *(const bf16x8*)(Bs + (wn * 64 + nf * 16 + l15) * 64 + kc * 32 + quarter * 8);
#pragma unroll
      for (int mf = 0; mf < 4; mf++)
#pragma unroll
        for (int nf = 0; nf < 4; nf++)
          acc[mf][nf] = __builtin_amdgcn_mfma_f32_16x16x32_bf16(af[mf], bfr[nf], acc[mf][nf], 0, 0, 0);
    }
  }
  if constexpr (MODE == 2) {
    if (bn >= 3072 && wn == 0) {
#pragma unroll
      for (int mf = 0; mf < 4; mf++)
#pragma unroll
        for (int r2 = 0; r2 < 4; r2++) {
          int t = bm + wm * 64 + mf * 16 + quarter * 4 + r2;
#pragma unroll
          for (int nf = 0; nf < 2; nf++) {
            int i = nf * 16 + l15;
            float c = cosb[t * 32 + i], s = sinb[t * 32 + i];
            float x1 = acc[mf][nf][r2], x2 = acc[mf][nf + 2][r2];
            acc[mf][nf][r2]     = x1 * c - x2 * s;
            acc[mf][nf + 2][r2] = x1 * s + x2 * c;
          }
        }
    }
  }
#pragma unroll
  for (int mf = 0; mf < 4; mf++)
#pragma unroll
    for (int nf = 0; nf < 4; nf++)
#pragma unroll
      for (int r2 = 0; r2 < 4; r2++) {
        int grow = bm + wm * 64 + mf * 16 + quarter * 4 + r2;
        int gcol = bn + wn * 64 + nf * 16 + l15;
        if (gcol < N)
          ((unsigned short*)C)[(size_t)grow * ldc + gcol] = f2b(acc[mf][nf][r2]);
      }
}

// ================= bf16 MFMA GEMM, 128x64 tile (for low-block-count shapes) =================
// MODE: 0 = f32 out, 1 = bf16 out. 4 waves, each owns a 32x64 strip. XCD-swizzled grid.
template<int MODE>
__global__ __launch_bounds__(256) void k_gemm_n64(
    const unsigned short* __restrict__ A, int lda,
    const unsigned short* __restrict__ Bt, int K,
    void* __restrict__ C, int ldc, int N) {
  __shared__ unsigned short As[128 * 64];
  __shared__ unsigned short Bs[64 * 64];
  int nwg = gridDim.x * gridDim.y;
  int orig = blockIdx.y * gridDim.x + blockIdx.x;
  int q = nwg >> 3, r = nwg & 7;
  int xcd = orig & 7, sub = orig >> 3;
  int wgid = (xcd < r ? xcd * (q + 1) : r * (q + 1) + (xcd - r) * q) + sub;
  int by = wgid / gridDim.x, bx = wgid - by * gridDim.x;
  const int bm = by * 128, bn = bx * 64;
  const int tid = threadIdx.x;
  const int lane = tid & 63, w = tid >> 6;
  const int l15 = lane & 15, quarter = lane >> 4;
  const int srow = (lane >> 3), scol = (lane & 7) * 8;

  f32x4 acc[2][4];
#pragma unroll
  for (int i = 0; i < 2; i++)
#pragma unroll
    for (int j = 0; j < 4; j++) acc[i][j] = (f32x4){0.f, 0.f, 0.f, 0.f};

  for (int k0 = 0; k0 < K; k0 += 64) {
    __syncthreads();
#pragma unroll
    for (int i = 0; i < 4; i++) {
      int r0 = w * 32 + i * 8;
      gload16(A + (size_t)(bm + r0 + srow) * lda + k0 + scol, &As[r0 * 64]);
    }
#pragma unroll
    for (int i = 0; i < 2; i++) {
      int r0 = w * 16 + i * 8;
      gload16(Bt + (size_t)(bn + r0 + srow) * K + k0 + scol, &Bs[r0 * 64]);
    }
    __syncthreads();
#pragma unroll
    for (int kc = 0; kc < 2; kc++) {
      bf16x8 af[2], bfr[4];
#pragma unroll
      for (int mf = 0; mf < 2; mf++)
        af[mf] = *(const bf16x8*)(As + (w * 32 + mf * 16 + l15) * 64 + kc * 32 + quarter * 8);
#pragma unroll
      for (int nf = 0; nf < 4; nf++)
        bfr[nf] = *(const bf16x8*)(Bs + (nf * 16 + l15) * 64 + kc * 32 + quarter * 8);
#pragma unroll
      for (int mf = 0; mf < 2; mf++)
#pragma unroll
        for (int nf = 0; nf < 4; nf++)
          acc[mf][nf] = __builtin_amdgcn_mfma_f32_16x16x32_bf16(af[mf], bfr[nf], acc[mf][nf], 0, 0, 0);
    }
  }
#pragma unroll
  for (int mf = 0; mf < 2; mf++)
#pragma unroll
    for (int nf = 0; nf < 4; nf++)
#pragma unroll
      for (int r2 = 0; r2 < 4; r2++) {
        int grow = bm + w * 32 + mf * 16 + quarter * 4 + r2;
        int gcol = bn + nf * 16 + l15;
        if (gcol < N) {
          if constexpr (MODE == 0) ((float*)C)[(size_t)grow * ldc + gcol] = acc[mf][nf][r2];
          else ((unsigned short*)C)[(size_t)grow * ldc + gcol] = f2b(acc[mf][nf][r2]);
        }
      }
}

// ================= fused transpose+cast phase kernels =================
__device__ inline void tcast_tile(const float* __restrict__ W, int K, int N,
                                  unsigned short* __restrict__ dst,
                                  int r, int ntx, int tid, float (*T)[33]) {
  int xt = r % ntx, kt = r / ntx;
  int n0 = xt * 32, k0 = kt * 32;
#pragma unroll
  for (int i = 0; i < 4; i++) {
    int idx = tid + 256 * i;
    int rr = idx >> 5, c = idx & 31;
    T[rr][c] = W[(size_t)(k0 + rr) * N + n0 + c];
  }
  __syncthreads();
#pragma unroll
  for (int i = 0; i < 4; i++) {
    int idx = tid + 256 * i;
    int rr = idx >> 5, c = idx & 31;
    dst[(size_t)(n0 + rr) * K + k0 + c] = f2b(T[c][rr]);
  }
}

// merged phases 1+2: p1 -> WT1 (idxs alias) + hs cast; p2 -> WT2
__global__ __launch_bounds__(256) void k_tcast_p12(
    const float* __restrict__ Wq_a, const float* __restrict__ Wkv_a,
    const float* __restrict__ Wk_idx, const float* __restrict__ Ww_idx,
    const float* __restrict__ hs, unsigned short* __restrict__ hs_b,
    unsigned short* __restrict__ WT1,
    const float* __restrict__ Wq_b, const float* __restrict__ Wq_idx,
    unsigned short* __restrict__ WT2) {
  __shared__ float T[32][33];
  int bid = blockIdx.x, tid = threadIdx.x;
  if (bid < 3072)       tcast_tile(Wq_a,  2048, 1536, WT1,                        bid,         48, tid, T);
  else if (bid < 4224)  tcast_tile(Wkv_a, 2048,  576, WT1 + (size_t)1536 * 2048,  bid - 3072,  18, tid, T);
  else if (bid < 4480)  tcast_tile(Wk_idx,2048,  128, WT1 + (size_t)2112 * 2048,  bid - 4224,   4, tid, T);
  else if (bid < 4608) {
    int idx = (bid - 4480) * 256 + tid;
    int k = idx >> 4, n = idx & 15;
    WT1[(size_t)(2240 + n) * 2048 + k] = f2b(Ww_idx[(size_t)k * 16 + n]);
  } else if (bid < 8704) {
    int idx = ((bid - 4608) * 256 + tid) * 4;
    const float* ip = hs + idx;
    unsigned short* op = hs_b + idx;
    op[0] = f2b(ip[0]); op[1] = f2b(ip[1]); op[2] = f2b(ip[2]); op[3] = f2b(ip[3]);
  }
  else if (bid < 13312) tcast_tile(Wq_b,   1536, 3072, WT2,                        bid - 8704,  96, tid, T);
  else                  tcast_tile(Wq_idx, 1536, 2048, WT2 + (size_t)3072 * 1536,  bid - 13312, 64, tid, T);
}

__global__ __launch_bounds__(256) void k_tcast_p3(
    const float* __restrict__ Wkv_b, const float* __restrict__ Wo,
    unsigned short* __restrict__ WT) {
  __shared__ float T[32][33];
  int bid = blockIdx.x, tid = threadIdx.x;
  if (bid < 2048) tcast_tile(Wkv_b,  512, 4096, WT,                       bid,        128, tid, T);
  else            tcast_tile(Wo,    2048, 2048, WT + (size_t)4096 * 512,  bid - 2048,  64, tid, T);
}

// ================= fused norms: qa-rms, kv-rms, kpe-rope, ki-ln-rope =================
__global__ __launch_bounds__(256) void k_norms(
    const float* __restrict__ fat, int stride,
    const float* __restrict__ qg, const float* __restrict__ kvg,
    const float* __restrict__ kng, const float* __restrict__ knb,
    const float* __restrict__ cosb, const float* __restrict__ sinb,
    unsigned short* __restrict__ qa_b, unsigned short* __restrict__ kvc_b,
    unsigned short* __restrict__ kpe_b, unsigned short* __restrict__ ki_b) {
  int t = blockIdx.x, tid = threadIdx.x;
  const float* p = fat + (size_t)t * stride;
  __shared__ float red[256];
  __shared__ float buf[128];
  float x[6]; float s = 0.f;
#pragma unroll
  for (int i = 0; i < 6; i++) { x[i] = p[tid + 256 * i]; s += x[i] * x[i]; }
  red[tid] = s; __syncthreads();
  for (int st = 128; st > 0; st >>= 1) { if (tid < st) red[tid] += red[tid + st]; __syncthreads(); }
  float scl = rsqrtf(red[0] * (1.f / 1536.f) + EPS_F);
#pragma unroll
  for (int i = 0; i < 6; i++)
    qa_b[(size_t)t * 1536 + tid + 256 * i] = f2b(x[i] * scl * qg[tid + 256 * i]);
  __syncthreads();
  float y0 = p[1536 + tid], y1 = p[1792 + tid];
  red[tid] = y0 * y0 + y1 * y1; __syncthreads();
  for (int st = 128; st > 0; st >>= 1) { if (tid < st) red[tid] += red[tid + st]; __syncthreads(); }
  float scl2 = rsqrtf(red[0] * (1.f / 512.f) + EPS_F);
  kvc_b[(size_t)t * 512 + tid]       = f2b(y0 * scl2 * kvg[tid]);
  kvc_b[(size_t)t * 512 + 256 + tid] = f2b(y1 * scl2 * kvg[256 + tid]);
  if (tid < 32) {
    float a = p[2048 + tid], b = p[2080 + tid];
    float c = cosb[t * 32 + tid], sn = sinb[t * 32 + tid];
    kpe_b[(size_t)t * 64 + tid]      = f2b(a * c - b * sn);
    kpe_b[(size_t)t * 64 + 32 + tid] = f2b(a * sn + b * c);
  }
  __syncthreads();
  float z = (tid < 128) ? p[2112 + tid] : 0.f;
  red[tid] = z; __syncthreads();
  for (int st = 128; st > 0; st >>= 1) { if (tid < st) red[tid] += red[tid + st]; __syncthreads(); }
  float mean = red[0] * (1.f / 128.f);
  __syncthreads();
  float d = (tid < 128) ? (z - mean) : 0.f;
  red[tid] = d * d; __syncthreads();
  for (int st = 128; st > 0; st >>= 1) { if (tid < st) red[tid] += red[tid + st]; __syncthreads(); }
  float var = red[0] * (1.f / 128.f);
  if (tid < 128) buf[tid] = d * rsqrtf(var + EPS_F) * kng[tid] + knb[tid];
  __syncthreads();
  if (tid < 128) {
    float outv;
    if (tid < 32) {
      float c = cosb[t * 32 + tid], sn = sinb[t * 32 + tid];
      outv = buf[tid] * c - buf[tid + 32] * sn;
    } else if (tid < 64) {
      int j = tid - 32;
      float c = cosb[t * 32 + j], sn = sinb[t * 32 + j];
      outv = buf[j] * sn + buf[tid] * c;
    } else outv = buf[tid];
    ki_b[(size_t)t * 128 + tid] = f2b(outv);
  }
}

// ================= indexer scores via MFMA: 64x64 causal tiles =================
__global__ __launch_bounds__(256) void k_idx_mfma(
    const unsigned short* __restrict__ qi_b, int qpitch,
    const unsigned short* __restrict__ ki_b,
    const float* __restrict__ wb, int wstride,
    float* __restrict__ out) {
  int bid = blockIdx.x;
  int tb = (int)((sqrtf(8.f * bid + 1.f) - 1.f) * 0.5f);
  while ((tb + 1) * (tb + 2) / 2 <= bid) tb++;
  while (tb * (tb + 1) / 2 > bid) tb--;
  int sb = bid - tb * (tb + 1) / 2;
  int t0 = tb * 64, s0 = sb * 64;

  int tid = threadIdx.x, lane = tid & 63, w = tid >> 6;
  int wm = w >> 1, wn = w & 1;
  int l15 = lane & 15, quarter = lane >> 4;

  __shared__ unsigned short Ks[64 * 128];
  __shared__ unsigned short Qs[2][64 * 128];
  __shared__ float Ws[64][16];

  int srow_[4], scc_[4];
#pragma unroll
  for (int i = 0; i < 4; i++) {
    int row = w * 16 + i * 4 + (lane >> 4);
    srow_[i] = row;
    scc_[i] = (lane & 15) ^ (row & 7);
  }
#pragma unroll
  for (int i = 0; i < 4; i++) {
    gload16(ki_b + (size_t)(s0 + srow_[i]) * 128 + scc_[i] * 8, &Ks[(w * 16 + i * 4) * 128]);
    gload16(qi_b + (size_t)(t0 + srow_[i]) * qpitch + scc_[i] * 8, &Qs[0][(w * 16 + i * 4) * 128]);
  }
  for (int i = tid; i < 64 * 16; i += 256) Ws[i >> 4][i & 15] = wb[(size_t)(t0 + (i >> 4)) * wstride + (i & 15)];
  __syncthreads();

  bf16x8 bfr[2][4];
#pragma unroll
  for (int nf = 0; nf < 2; nf++) {
    int row = wn * 32 + nf * 16 + l15;
    int rx = (row & 7) << 3;
#pragma unroll
    for (int kc = 0; kc < 4; kc++)
      bfr[nf][kc] = *(const bf16x8*)(Ks + row * 128 + ((kc * 32 + quarter * 8) ^ rx));
  }

  f32x4 acc[2][2];
#pragma unroll
  for (int mf = 0; mf < 2; mf++)
#pragma unroll
    for (int nf = 0; nf < 2; nf++) acc[mf][nf] = (f32x4){0.f, 0.f, 0.f, 0.f};

  for (int h = 0; h < 16; h++) {
    int cur = h & 1;
    if (h < 15) {
#pragma unroll
      for (int i = 0; i < 4; i++)
        gload16(qi_b + (size_t)(t0 + srow_[i]) * qpitch + (h + 1) * 128 + scc_[i] * 8,
                &Qs[cur ^ 1][(w * 16 + i * 4) * 128]);
    }
    f32x4 acch[2][2];
#pragma unroll
    for (int mf = 0; mf < 2; mf++)
#pragma unroll
      for (int nf = 0; nf < 2; nf++) acch[mf][nf] = (f32x4){0.f, 0.f, 0.f, 0.f};

    __builtin_amdgcn_s_setprio(1);
#pragma unroll
    for (int mf = 0; mf < 2; mf++) {
      int row = wm * 32 + mf * 16 + l15;
      int rx = (row & 7) << 3;
      bf16x8 af[4];
#pragma unroll
      for (int kc = 0; kc < 4; kc++)
        af[kc] = *(const bf16x8*)(Qs[cur] + row * 128 + ((kc * 32 + quarter * 8) ^ rx));
#pragma unroll
      for (int nf = 0; nf < 2; nf++)
#pragma unroll
        for (int kc = 0; kc < 4; kc++)
          acch[mf][nf] = __builtin_amdgcn_mfma_f32_16x16x32_bf16(af[kc], bfr[nf][kc], acch[mf][nf], 0, 0, 0);
    }
    __builtin_amdgcn_s_setprio(0);
#pragma unroll
    for (int mf = 0; mf < 2; mf++) {
#pragma unroll
      for (int r = 0; r < 4; r++) {
        float wv = Ws[wm * 32 + mf * 16 + quarter * 4 + r][h];
#pragma unroll
        for (int nf = 0; nf < 2; nf++)
          acc[mf][nf][r] = fmaf(wv, fmaxf(acch[mf][nf][r], 0.f), acc[mf][nf][r]);
      }
    }
    __syncthreads();
  }
#pragma unroll
  for (int mf = 0; mf < 2; mf++)
#pragma unroll
    for (int nf = 0; nf < 2; nf++)
#pragma unroll
      for (int r = 0; r < 4; r++) {
        int t = t0 + wm * 32 + mf * 16 + quarter * 4 + r;
        int s = s0 + wn * 32 + nf * 16 + l15;
        out[(size_t)t * 2048 + s] = acc[mf][nf][r] * ISCALE_ID;
      }
}

// ================= per-row top-K -> bitmask (wave-scan radix select) =================
__global__ __launch_bounds__(256) void k_topk_mask(const float* __restrict__ idx_sc, u64* __restrict__ maskw) {
  int t = blockIdx.x;
  int tid = threadIdx.x;
  int n = t + 1;
  if (n <= TOPKC) {
    if (tid < 32) {
      int lo = tid * 64, hi = lo + 63;
      u64 wv;
      if (t >= hi) wv = ~0ULL;
      else if (t < lo) wv = 0ULL;
      else wv = (~0ULL) >> (63 - (t - lo));
      maskw[(size_t)t * 32 + tid] = wv;
    }
    return;
  }
  __shared__ unsigned int u[2048];
  __shared__ int hist[256];
  __shared__ int wtot[4];
  __shared__ u64 mw[32];
  __shared__ int sel_b, new_target;
  __shared__ int cnt[32];
  __shared__ u64 tmask[32];
  int lane = tid & 63, wid = tid >> 6;
  if (tid < 32) mw[tid] = 0ULL;
  const float* row = idx_sc + (size_t)t * 2048;
  for (int s = tid; s < n; s += 256) {
    unsigned int bb = __float_as_uint(row[s]);
    u[s] = (bb & 0x80000000u) ? ~bb : (bb | 0x80000000u);
  }
  unsigned int prefix = 0;
  int target = TOPKC;
  for (int shift = 24; shift >= 0; shift -= 8) {
    hist[tid] = 0;
    __syncthreads();
    unsigned int himask = (shift == 24) ? 0u : (0xFFFFFFFFu << (shift + 8));
    for (int s = tid; s < n; s += 256) {
      unsigned int uv = u[s];
      if ((uv & himask) == prefix) atomicAdd(&hist[(uv >> shift) & 0xFF], 1);
    }
    __syncthreads();
    int h = hist[tid];
    int sum = h;
#pragma unroll
    for (int off = 1; off < 64; off <<= 1) {
      int tv = __shfl_down(sum, off);
      if (lane + off < 64) sum += tv;
    }
    if (lane == 0) wtot[wid] = sum;
    __syncthreads();
    int scan = sum;
    for (int wI = wid + 1; wI < 4; wI++) scan += wtot[wI];
    if (scan >= target && scan - h < target) {
      sel_b = tid;
      new_target = target - (scan - h);
    }
    __syncthreads();
    prefix |= ((unsigned int)sel_b) << shift;
    target = new_target;
  }
#pragma unroll
  for (int i = 0; i < 8; i++) {
    int s = i * 256 + tid;
    bool in = (s < n);
    unsigned int uv = in ? u[s] : 0u;
    bool tie = in && (uv == prefix);
    u64 bal = __ballot(tie);
    if (lane == 0) { int c = i * 4 + wid; cnt[c] = __popcll(bal); tmask[c] = bal; }
    if (in && uv > prefix) atomicOr(&mw[s >> 6], 1ULL << (s & 63));
  }
  __syncthreads();
#pragma unroll
  for (int i = 0; i < 8; i++) {
    int s = i * 256 + tid;
    if (s >= n) continue;
    if (u[s] != prefix) continue;
    int c = i * 4 + wid;
    int base = 0;
    for (int c2 = 0; c2 < c; c2++) base += cnt[c2];
    int rank = base + __popcll(tmask[c] & ((1ULL << lane) - 1ULL));
    if (rank < target) atomicOr(&mw[s >> 6], 1ULL << (s & 63));
  }
  __syncthreads();
  if (tid < 32) maskw[(size_t)t * 32 + tid] = mw[tid];
}

// ================= MFMA flash attention: r12 structure + T5 setprio around MFMA clusters =================
__global__ __launch_bounds__(256) void k_attn_mfma(
    const unsigned short* __restrict__ qb, int qpitch,
    const unsigned short* __restrict__ kvb_b,
    const unsigned short* __restrict__ kpe_b,
    const float* __restrict__ cosb, const float* __restrict__ sinb,
    const u64* __restrict__ maskw,
    unsigned short* __restrict__ attn_b) {
  int ybm = blockIdx.x;
  int h = blockIdx.y;
  int yb = (h < 8) ? ybm : (31 - ybm);
  int t0 = yb * 64;
  int tid = threadIdx.x;
  int lane = tid & 63, wq = tid >> 6;
  int quarter = lane >> 4, l15 = lane & 15;

  __shared__ unsigned short Kd[2][64 * 192];
  __shared__ unsigned short Vts[128 * 64];

  const unsigned short* kb_base[6];
  int kb_step[6];
#pragma unroll
  for (int i = 0; i < 6; i++) {
    int slot = (wq * 6 + i) * 1024 + lane * 16;
    int rowk = slot / 384;
    int coff = slot - rowk * 384;
    int cc = (coff ^ ((rowk & 7) << 4)) >> 4;
    if (cc < 16) { kb_base[i] = kvb_b + (size_t)rowk * 4096 + h * 256 + cc * 8; kb_step[i] = 4096; }
    else         { kb_base[i] = kpe_b + (size_t)rowk * 64 + (cc - 16) * 8;      kb_step[i] = 64; }
  }
  const int vdg = tid & 15, vsp = tid >> 4;
  const unsigned short* vbase = kvb_b + (size_t)(vsp * 4) * 4096 + h * 256 + 128 + vdg * 8;

  bf16x8 qf[6];
  {
    int t = t0 + wq * 16 + l15;
    const unsigned short* qp = qb + (size_t)t * qpitch + h * 192 + quarter * 8;
#pragma unroll
    for (int kc = 0; kc < 6; kc++) qf[kc] = *(const bf16x8*)(qp + kc * 32);
    const float* cp = cosb + t * 32 + quarter * 8;
    const float* sp = sinb + t * 32 + quarter * 8;
    float4 ca = *(const float4*)cp,  cb2 = *(const float4*)(cp + 4);
    float4 sa = *(const float4*)sp,  sb2 = *(const float4*)(sp + 4);
    float carr[8] = {ca.x, ca.y, ca.z, ca.w, cb2.x, cb2.y, cb2.z, cb2.w};
    float sarr[8] = {sa.x, sa.y, sa.z, sa.w, sb2.x, sb2.y, sb2.z, sb2.w};
#pragma unroll
    for (int j = 0; j < 8; j++) {
      float x1 = b2f((unsigned short)qf[4][j]);
      float x2 = b2f((unsigned short)qf[5][j]);
      qf[4][j] = (short)f2b(x1 * carr[j] - x2 * sarr[j]);
      qf[5][j] = (short)f2b(x1 * sarr[j] + x2 * carr[j]);
    }
  }

  f32x4 o[8];
#pragma unroll
  for (int df = 0; df < 8; df++) o[df] = (f32x4){0.f, 0.f, 0.f, 0.f};
  float mcol = -__builtin_inff(), lcol = 0.f;
  const u64* mrow = maskw + (size_t)(t0 + wq * 16 + l15) * 32;
  int nsb = yb + 1;

#pragma unroll
  for (int i = 0; i < 6; i++) gload16(kb_base[i], &Kd[0][(wq * 6 + i) * 512]);
  bf16x8 vr0 = *(const bf16x8*)(vbase);
  bf16x8 vr1 = *(const bf16x8*)(vbase + 4096);
  bf16x8 vr2 = *(const bf16x8*)(vbase + 8192);
  bf16x8 vr3 = *(const bf16x8*)(vbase + 12288);
  __syncthreads();
#pragma unroll
  for (int j = 0; j < 8; j++) {
    int d = vdg * 8 + j;
    uint2 w2;
    w2.x = (unsigned)(unsigned short)vr0[j] | (((unsigned)(unsigned short)vr1[j]) << 16);
    w2.y = (unsigned)(unsigned short)vr2[j] | (((unsigned)(unsigned short)vr3[j]) << 16);
    *(uint2*)((char*)Vts + d * 128 + ((vsp * 8) ^ (((d >> 2) & 7) << 4))) = w2;
  }

  for (int sb = 0; sb < nsb; sb++) {
    int cur = sb & 1;
    __syncthreads();
    bool pf = (sb + 1 < nsb);
    if (pf) {
      size_t sn = (size_t)(sb + 1) * 64;
#pragma unroll
      for (int i = 0; i < 6; i++)
        gload16(kb_base[i] + sn * kb_step[i], &Kd[cur ^ 1][(wq * 6 + i) * 512]);
      const unsigned short* vp = vbase + sn * 4096;
      vr0 = *(const bf16x8*)(vp);
      vr1 = *(const bf16x8*)(vp + 4096);
      vr2 = *(const bf16x8*)(vp + 8192);
      vr3 = *(const bf16x8*)(vp + 12288);
    }
    const unsigned short* Kc = Kd[cur];
    f32x4 sfT[4];
    __builtin_amdgcn_s_setprio(1);
#pragma unroll
    for (int sc = 0; sc < 4; sc++) {
      f32x4 a = (f32x4){0.f, 0.f, 0.f, 0.f};
      int row = sc * 16 + l15;
      int rx = (row & 7) << 4;
#pragma unroll
      for (int kc = 0; kc < 6; kc++) {
        int byte = row * 384 + ((kc * 64 + quarter * 16) ^ rx);
        bf16x8 kf = *(const bf16x8*)((const char*)Kc + byte);
        a = __builtin_amdgcn_mfma_f32_16x16x32_bf16(kf, qf[kc], a, 0, 0, 0);
      }
      sfT[sc] = a;
    }
    __builtin_amdgcn_s_setprio(0);
    u64 w64 = mrow[sb];
    float p[4][4];
#pragma unroll
    for (int sc = 0; sc < 4; sc++)
#pragma unroll
      for (int r = 0; r < 4; r++) {
        int sbit = sc * 16 + quarter * 4 + r;
        bool sel = (w64 >> sbit) & 1ULL;
        p[sc][r] = sel ? sfT[sc][r] * SCALE_ATTN : -__builtin_inff();
      }
    float v = p[0][0];
#pragma unroll
    for (int sc = 0; sc < 4; sc++)
#pragma unroll
      for (int r = 0; r < 4; r++) v = fmaxf(v, p[sc][r]);
    v = fmaxf(v, __shfl_xor(v, 16));
    v = fmaxf(v, __shfl_xor(v, 32));
    float mn = fmaxf(mcol, v);
    bool dead = (mn == -__builtin_inff());
    float scl = dead ? 1.f : __expf(mcol - mn);
#pragma unroll
    for (int sc = 0; sc < 4; sc++)
#pragma unroll
      for (int r = 0; r < 4; r++)
        p[sc][r] = dead ? 0.f : __expf(p[sc][r] - mn);
    mcol = dead ? mcol : mn;
    float rs = 0.f;
#pragma unroll
    for (int sc = 0; sc < 4; sc++)
#pragma unroll
      for (int r = 0; r < 4; r++) rs += p[sc][r];
    rs += __shfl_xor(rs, 16);
    rs += __shfl_xor(rs, 32);
    lcol = lcol * scl + rs;

    unsigned pk[4][2];
#pragma unroll
    for (int sc = 0; sc < 4; sc++)
#pragma unroll
      for (int rr = 0; rr < 2; rr++)
        pk[sc][rr] = (unsigned)f2b(p[sc][2 * rr]) | (((unsigned)f2b(p[sc][2 * rr + 1])) << 16);
    bf16x8 pa[2];
#pragma unroll
    for (int kc = 0; kc < 2; kc++) {
      union { unsigned d[4]; bf16x8 v; } pu;
#pragma unroll
      for (int jj = 0; jj < 4; jj++) {
        int src = ((quarter & 1) * 2 + (jj >> 1)) * 16 + l15;
        unsigned lo = (unsigned)__shfl((int)pk[kc * 2][jj & 1], src);
        unsigned hi = (unsigned)__shfl((int)pk[kc * 2 + 1][jj & 1], src);
        pu.d[jj] = (quarter < 2) ? lo : hi;
      }
      pa[kc] = pu.v;
    }
    float sclr[4];
#pragma unroll
    for (int r = 0; r < 4; r++) sclr[r] = __shfl(scl, quarter * 4 + r);
#pragma unroll
    for (int df = 0; df < 8; df++)
#pragma unroll
      for (int r = 0; r < 4; r++) o[df][r] *= sclr[r];
    __builtin_amdgcn_s_setprio(1);
#pragma unroll
    for (int kc = 0; kc < 2; kc++)
#pragma unroll
      for (int df = 0; df < 8; df++) {
        int d = df * 16 + l15;
        int vbyte = d * 128 + ((kc * 64 + quarter * 16) ^ (((d >> 2) & 7) << 4));
        bf16x8 vf = *(const bf16x8*)((const char*)Vts + vbyte);
        o[df] = __builtin_amdgcn_mfma_f32_16x16x32_bf16(pa[kc], vf, o[df], 0, 0, 0);
      }
    __builtin_amdgcn_s_setprio(0);
    __syncthreads();
    if (pf) {
#pragma unroll
      for (int j = 0; j < 8; j++) {
        int d = vdg * 8 + j;
        uint2 w2;
        w2.x = (unsigned)(unsigned short)vr0[j] | (((unsigned)(unsigned short)vr1[j]) << 16);
        w2.y = (unsigned)(unsigned short)vr2[j] | (((unsigned)(unsigned short)vr3[j]) << 16);
        *(uint2*)((char*)Vts + d * 128 + ((vsp * 8) ^ (((d >> 2) & 7) << 4))) = w2;
      }
    }
  }
  float inv = (lcol > 0.f) ? 1.f / lcol : 0.f;
  float invr[4];
#pragma unroll
  for (int r = 0; r < 4; r++) invr[r] = __shfl(inv, quarter * 4 + r);
#pragma unroll
  for (int r = 0; r < 4; r++) {
    int t = t0 + wq * 16 + quarter * 4 + r;
    unsigned short* op = attn_b + (size_t)t * 2048 + h * 128 + l15;
#pragma unroll
    for (int df = 0; df < 8; df++) op[df * 16] = f2b(o[df][r] * invr[r]);
  }
}

// ================= host launch =================
extern "C" void kernel_launch(void* const* d_in, const int* in_sizes, int n_in,
                              void* d_out, int out_size, void* d_ws, size_t ws_size,
                              hipStream_t stream) {
  const float* hs     = (const float*)d_in[0];
  const float* cosb   = (const float*)d_in[1];
  const float* sinb   = (const float*)d_in[2];
  const float* Wq_a   = (const float*)d_in[3];
  const float* q_a_g  = (const float*)d_in[4];
  const float* Wq_b   = (const float*)d_in[5];
  const float* Wkv_a  = (const float*)d_in[6];
  const float* kv_a_g = (const float*)d_in[7];
  const float* Wkv_b  = (const float*)d_in[8];
  const float* Wo     = (const float*)d_in[9];
  const float* Wq_idx = (const float*)d_in[10];
  const float* Wk_idx = (const float*)d_in[11];
  const float* Ww_idx = (const float*)d_in[12];
  const float* kn_g   = (const float*)d_in[13];
  const float* kn_b   = (const float*)d_in[14];
  float* out = (float*)d_out;

  char* base = (char*)d_ws;
  size_t off = 0;
  auto alloc = [&](size_t bytes) { void* p = base + off; off += (bytes + 255) & ~size_t(255); return p; };

  // fat1 f32 [2048][2304]: qa | kv | kpe | ki | wb(2240..2255); later attn_b (bf16)
  float* fat1 = (float*)alloc((size_t)S_ * 2304 * 4);
  unsigned short* attn_b = (unsigned short*)fat1;
  // idxs f32 [2048][2048]; WT1 (phase-1 weights) aliases it (dead by idx_mfma)
  float* idxs = (float*)alloc((size_t)S_ * 2048 * 4);
  unsigned short* WT1 = (unsigned short*)idxs;
  // fat2 bf16 [2048][5120]: qb | qi
  unsigned short* fat2 = (unsigned short*)alloc((size_t)S_ * 5120 * 2);
  u64*   maskw = (u64*)alloc((size_t)S_ * 32 * 8);
  unsigned short* hs_b  = (unsigned short*)alloc((size_t)S_ * 2048 * 2);
  unsigned short* qa_b  = (unsigned short*)alloc((size_t)S_ * 1536 * 2);
  unsigned short* kvc_b = (unsigned short*)alloc((size_t)S_ * 512 * 2);
  unsigned short* kpe_b = (unsigned short*)alloc((size_t)S_ * 64 * 2);
  unsigned short* kvb_b = (unsigned short*)alloc((size_t)S_ * 4096 * 2);
  unsigned short* ki_b  = (unsigned short*)alloc((size_t)S_ * 128 * 2);
  unsigned short* WT    = (unsigned short*)alloc((size_t)5120 * 1536 * 2);

  dim3 blk(256);

  // merged phase-1+2 weights + hs cast (one launch; p1 -> WT1 alias, p2 -> WT)
  k_tcast_p12<<<dim3(16384), blk, 0, stream>>>(Wq_a, Wkv_a, Wk_idx, Ww_idx, hs, hs_b, WT1,
                                               Wq_b, Wq_idx, WT);
  // fused hs-GEMM: N=2256 into fat1 (128x64 tiles, 576 blocks)
  k_gemm_n64<0><<<dim3(36, 16), blk, 0, stream>>>(hs_b, 2048, WT1, 2048, fat1, 2304, 2256);
  // fused norms
  k_norms<<<dim3(S_), blk, 0, stream>>>(fat1, 2304, q_a_g, kv_a_g, kn_g, kn_b, cosb, sinb,
                                        qa_b, kvc_b, kpe_b, ki_b);
  // fused qa-GEMM with qi-RoPE fused into the epilogue (MODE 2)
  k_gemm_bf16<2><<<dim3(40, 16), blk, 0, stream>>>(qa_b, 1536, WT, 1536, fat2, 5120, 5120, cosb, sinb);
  // phase-3 weights: [Wkv_b | Wo]^T -> WT
  k_tcast_p3<<<dim3(6144), blk, 0, stream>>>(Wkv_b, Wo, WT);
  // kvb = kv_c @ Wkv_b (128x64 tiles, 1024 blocks, bf16 out)
  k_gemm_n64<1><<<dim3(64, 16), blk, 0, stream>>>(kvc_b, 512, WT, 512, kvb_b, 4096, 4096);
  // indexer scores (triangular grid); wb from fat1 cols 2240.., stride 2304 (overwrites WT1 alias)
  k_idx_mfma<<<dim3(528), blk, 0, stream>>>(fat2 + 3072, 5120, ki_b, fat1 + 2240, 2304, idxs);
  // top-512 per row -> bitmask
  k_topk_mask<<<dim3(S_), blk, 0, stream>>>(idxs, maskw);
  // flash attention (r12 structure + T5) -> attn_b (aliases fat1)
  k_attn_mfma<<<dim3(32, 16), blk, 0, stream>>>(fat2, 5120, kvb_b, kpe_b, cosb, sinb, maskw, attn_b);
  // out = attn @ Wo (128x64 tiles, 512 blocks; WT second slot)
  k_gemm_n64<0><<<dim3(32, 16), blk, 0, stream>>>(attn_b, 2048, WT + (size_t)4096 * 512, 2048, out, 2048, 2048);

  (void)in_sizes; (void)n_in; (void)out_size; (void)ws_size;
}

// Round 18
// 335.972 us; speedup vs baseline: 1.2004x; 1.2004x over previous
//
#include <hip/hip_runtime.h>
#include <cstdint>
#include <cstddef>
#include <cmath>

typedef unsigned long long u64;
typedef __attribute__((ext_vector_type(8))) short bf16x8;   // 8 bf16 in 4 VGPRs
typedef __attribute__((ext_vector_type(4))) float f32x4;

static constexpr int S_    = 2048;
static constexpr int H_    = 2048;
static constexpr int TOPKC = 512;

#define SCALE_ATTN 0.07216878364870323f   // (192)^-0.5
#define ISCALE_ID  0.08838834764831845f   // (128)^-0.5
#define EPS_F 1e-6f

__device__ inline unsigned short f2b(float f) {
  unsigned u = __float_as_uint(f);
  return (unsigned short)((u + 0x7FFFu + ((u >> 16) & 1u)) >> 16);
}
__device__ inline float b2f(unsigned short b) {
  return __uint_as_float(((unsigned)b) << 16);
}
// async global->LDS, 16B per lane; LDS dest = wave-uniform base + lane*16, global src per-lane
__device__ inline void gload16(const unsigned short* g, unsigned short* l) {
  __builtin_amdgcn_global_load_lds((const __attribute__((address_space(1))) void*)g,
                                   (__attribute__((address_space(3))) void*)l, 16, 0, 0);
}

// ================= bf16 MFMA GEMM: C[M,N] = A[M,K] @ Bt[N,K]^T (XCD-swizzled grid) =================
// MODE: 1 = bf16 out, 2 = bf16 out + fused RoPE on cols>=3072 (qi, head=128, first 64)
template<int MODE>
__global__ __launch_bounds__(256) void k_gemm_bf16(
    const unsigned short* __restrict__ A, int lda,
    const unsigned short* __restrict__ Bt, int K,
    void* __restrict__ C, int ldc, int N,
    const float* __restrict__ cosb, const float* __restrict__ sinb) {
  __shared__ unsigned short As[128 * 64];
  __shared__ unsigned short Bs[128 * 64];
  // XCD-aware bijective remap (m204)
  int nwg = gridDim.x * gridDim.y;
  int orig = blockIdx.y * gridDim.x + blockIdx.x;
  int q = nwg >> 3, r = nwg & 7;
  int xcd = orig & 7, sub = orig >> 3;
  int wgid = (xcd < r ? xcd * (q + 1) : r * (q + 1) + (xcd - r) * q) + sub;
  int by = wgid / gridDim.x, bx = wgid - by * gridDim.x;
  const int bm = by * 128, bn = bx * 128;
  const int tid = threadIdx.x;
  const int lane = tid & 63, w = tid >> 6;
  const int wm = w >> 1, wn = w & 1;
  const int l15 = lane & 15, quarter = lane >> 4;
  const int srow = (lane >> 3), scol = (lane & 7) * 8;

  f32x4 acc[4][4];
#pragma unroll
  for (int i = 0; i < 4; i++)
#pragma unroll
    for (int j = 0; j < 4; j++) acc[i][j] = (f32x4){0.f, 0.f, 0.f, 0.f};

  for (int k0 = 0; k0 < K; k0 += 64) {
    __syncthreads();
#pragma unroll
    for (int i = 0; i < 4; i++) {
      int r0 = w * 32 + i * 8;
      gload16(A  + (size_t)(bm + r0 + srow) * lda + k0 + scol, &As[r0 * 64]);
      gload16(Bt + (size_t)(bn + r0 + srow) * K   + k0 + scol, &Bs[r0 * 64]);
    }
    __syncthreads();
#pragma unroll
    for (int kc = 0; kc < 2; kc++) {
      bf16x8 af[4], bfr[4];
#pragma unroll
      for (int mf = 0; mf < 4; mf++)
        af[mf] = *(const bf16x8*)(As + (wm * 64 + mf * 16 + l15) * 64 + kc * 32 + quarter * 8);
#pragma unroll
      for (int nf = 0; nf < 4; nf++)
        bfr[nf] = *(const bf16x8*)(Bs + (wn * 64 + nf * 16 + l15) * 64 + kc * 32 + quarter * 8);
#pragma unroll
      for (int mf = 0; mf < 4; mf++)
#pragma unroll
        for (int nf = 0; nf < 4; nf++)
          acc[mf][nf] = __builtin_amdgcn_mfma_f32_16x16x32_bf16(af[mf], bfr[nf], acc[mf][nf], 0, 0, 0);
    }
  }
  if constexpr (MODE == 2) {
    if (bn >= 3072 && wn == 0) {
#pragma unroll
      for (int mf = 0; mf < 4; mf++)
#pragma unroll
        for (int r2 = 0; r2 < 4; r2++) {
          int t = bm + wm * 64 + mf * 16 + quarter * 4 + r2;
#pragma unroll
          for (int nf = 0; nf < 2; nf++) {
            int i = nf * 16 + l15;
            float c = cosb[t * 32 + i], s = sinb[t * 32 + i];
            float x1 = acc[mf][nf][r2], x2 = acc[mf][nf + 2][r2];
            acc[mf][nf][r2]     = x1 * c - x2 * s;
            acc[mf][nf + 2][r2] = x1 * s + x2 * c;
          }
        }
    }
  }
#pragma unroll
  for (int mf = 0; mf < 4; mf++)
#pragma unroll
    for (int nf = 0; nf < 4; nf++)
#pragma unroll
      for (int r2 = 0; r2 < 4; r2++) {
        int grow = bm + wm * 64 + mf * 16 + quarter * 4 + r2;
        int gcol = bn + wn * 64 + nf * 16 + l15;
        if (gcol < N)
          ((unsigned short*)C)[(size_t)grow * ldc + gcol] = f2b(acc[mf][nf][r2]);
      }
}

// ================= bf16 MFMA GEMM, 128x64 tile (for low-block-count shapes) =================
// MODE: 0 = f32 out, 1 = bf16 out. 4 waves, each owns a 32x64 strip. XCD-swizzled grid.
template<int MODE>
__global__ __launch_bounds__(256) void k_gemm_n64(
    const unsigned short* __restrict__ A, int lda,
    const unsigned short* __restrict__ Bt, int K,
    void* __restrict__ C, int ldc, int N) {
  __shared__ unsigned short As[128 * 64];
  __shared__ unsigned short Bs[64 * 64];
  int nwg = gridDim.x * gridDim.y;
  int orig = blockIdx.y * gridDim.x + blockIdx.x;
  int q = nwg >> 3, r = nwg & 7;
  int xcd = orig & 7, sub = orig >> 3;
  int wgid = (xcd < r ? xcd * (q + 1) : r * (q + 1) + (xcd - r) * q) + sub;
  int by = wgid / gridDim.x, bx = wgid - by * gridDim.x;
  const int bm = by * 128, bn = bx * 64;
  const int tid = threadIdx.x;
  const int lane = tid & 63, w = tid >> 6;
  const int l15 = lane & 15, quarter = lane >> 4;
  const int srow = (lane >> 3), scol = (lane & 7) * 8;

  f32x4 acc[2][4];
#pragma unroll
  for (int i = 0; i < 2; i++)
#pragma unroll
    for (int j = 0; j < 4; j++) acc[i][j] = (f32x4){0.f, 0.f, 0.f, 0.f};

  for (int k0 = 0; k0 < K; k0 += 64) {
    __syncthreads();
#pragma unroll
    for (int i = 0; i < 4; i++) {
      int r0 = w * 32 + i * 8;
      gload16(A + (size_t)(bm + r0 + srow) * lda + k0 + scol, &As[r0 * 64]);
    }
#pragma unroll
    for (int i = 0; i < 2; i++) {
      int r0 = w * 16 + i * 8;
      gload16(Bt + (size_t)(bn + r0 + srow) * K + k0 + scol, &Bs[r0 * 64]);
    }
    __syncthreads();
#pragma unroll
    for (int kc = 0; kc < 2; kc++) {
      bf16x8 af[2], bfr[4];
#pragma unroll
      for (int mf = 0; mf < 2; mf++)
        af[mf] = *(const bf16x8*)(As + (w * 32 + mf * 16 + l15) * 64 + kc * 32 + quarter * 8);
#pragma unroll
      for (int nf = 0; nf < 4; nf++)
        bfr[nf] = *(const bf16x8*)(Bs + (nf * 16 + l15) * 64 + kc * 32 + quarter * 8);
#pragma unroll
      for (int mf = 0; mf < 2; mf++)
#pragma unroll
        for (int nf = 0; nf < 4; nf++)
          acc[mf][nf] = __builtin_amdgcn_mfma_f32_16x16x32_bf16(af[mf], bfr[nf], acc[mf][nf], 0, 0, 0);
    }
  }
#pragma unroll
  for (int mf = 0; mf < 2; mf++)
#pragma unroll
    for (int nf = 0; nf < 4; nf++)
#pragma unroll
      for (int r2 = 0; r2 < 4; r2++) {
        int grow = bm + w * 32 + mf * 16 + quarter * 4 + r2;
        int gcol = bn + nf * 16 + l15;
        if (gcol < N) {
          if constexpr (MODE == 0) ((float*)C)[(size_t)grow * ldc + gcol] = acc[mf][nf][r2];
          else ((unsigned short*)C)[(size_t)grow * ldc + gcol] = f2b(acc[mf][nf][r2]);
        }
      }
}

// ================= fused transpose+cast phase kernels =================
__device__ inline void tcast_tile(const float* __restrict__ W, int K, int N,
                                  unsigned short* __restrict__ dst,
                                  int r, int ntx, int tid, float (*T)[33]) {
  int xt = r % ntx, kt = r / ntx;
  int n0 = xt * 32, k0 = kt * 32;
#pragma unroll
  for (int i = 0; i < 4; i++) {
    int idx = tid + 256 * i;
    int rr = idx >> 5, c = idx & 31;
    T[rr][c] = W[(size_t)(k0 + rr) * N + n0 + c];
  }
  __syncthreads();
#pragma unroll
  for (int i = 0; i < 4; i++) {
    int idx = tid + 256 * i;
    int rr = idx >> 5, c = idx & 31;
    dst[(size_t)(n0 + rr) * K + k0 + c] = f2b(T[c][rr]);
  }
}

// merged phases 1+2: p1 -> WT1 (idxs alias) + hs cast; p2 -> WT2
__global__ __launch_bounds__(256) void k_tcast_p12(
    const float* __restrict__ Wq_a, const float* __restrict__ Wkv_a,
    const float* __restrict__ Wk_idx, const float* __restrict__ Ww_idx,
    const float* __restrict__ hs, unsigned short* __restrict__ hs_b,
    unsigned short* __restrict__ WT1,
    const float* __restrict__ Wq_b, const float* __restrict__ Wq_idx,
    unsigned short* __restrict__ WT2) {
  __shared__ float T[32][33];
  int bid = blockIdx.x, tid = threadIdx.x;
  if (bid < 3072)       tcast_tile(Wq_a,  2048, 1536, WT1,                        bid,         48, tid, T);
  else if (bid < 4224)  tcast_tile(Wkv_a, 2048,  576, WT1 + (size_t)1536 * 2048,  bid - 3072,  18, tid, T);
  else if (bid < 4480)  tcast_tile(Wk_idx,2048,  128, WT1 + (size_t)2112 * 2048,  bid - 4224,   4, tid, T);
  else if (bid < 4608) {
    int idx = (bid - 4480) * 256 + tid;
    int k = idx >> 4, n = idx & 15;
    WT1[(size_t)(2240 + n) * 2048 + k] = f2b(Ww_idx[(size_t)k * 16 + n]);
  } else if (bid < 8704) {
    int idx = ((bid - 4608) * 256 + tid) * 4;
    const float* ip = hs + idx;
    unsigned short* op = hs_b + idx;
    op[0] = f2b(ip[0]); op[1] = f2b(ip[1]); op[2] = f2b(ip[2]); op[3] = f2b(ip[3]);
  }
  else if (bid < 13312) tcast_tile(Wq_b,   1536, 3072, WT2,                        bid - 8704,  96, tid, T);
  else                  tcast_tile(Wq_idx, 1536, 2048, WT2 + (size_t)3072 * 1536,  bid - 13312, 64, tid, T);
}

__global__ __launch_bounds__(256) void k_tcast_p3(
    const float* __restrict__ Wkv_b, const float* __restrict__ Wo,
    unsigned short* __restrict__ WT) {
  __shared__ float T[32][33];
  int bid = blockIdx.x, tid = threadIdx.x;
  if (bid < 2048) tcast_tile(Wkv_b,  512, 4096, WT,                       bid,        128, tid, T);
  else            tcast_tile(Wo,    2048, 2048, WT + (size_t)4096 * 512,  bid - 2048,  64, tid, T);
}

// ================= fused norms: qa-rms, kv-rms, kpe-rope, ki-ln-rope =================
__global__ __launch_bounds__(256) void k_norms(
    const float* __restrict__ fat, int stride,
    const float* __restrict__ qg, const float* __restrict__ kvg,
    const float* __restrict__ kng, const float* __restrict__ knb,
    const float* __restrict__ cosb, const float* __restrict__ sinb,
    unsigned short* __restrict__ qa_b, unsigned short* __restrict__ kvc_b,
    unsigned short* __restrict__ kpe_b, unsigned short* __restrict__ ki_b) {
  int t = blockIdx.x, tid = threadIdx.x;
  const float* p = fat + (size_t)t * stride;
  __shared__ float red[256];
  __shared__ float buf[128];
  float x[6]; float s = 0.f;
#pragma unroll
  for (int i = 0; i < 6; i++) { x[i] = p[tid + 256 * i]; s += x[i] * x[i]; }
  red[tid] = s; __syncthreads();
  for (int st = 128; st > 0; st >>= 1) { if (tid < st) red[tid] += red[tid + st]; __syncthreads(); }
  float scl = rsqrtf(red[0] * (1.f / 1536.f) + EPS_F);
#pragma unroll
  for (int i = 0; i < 6; i++)
    qa_b[(size_t)t * 1536 + tid + 256 * i] = f2b(x[i] * scl * qg[tid + 256 * i]);
  __syncthreads();
  float y0 = p[1536 + tid], y1 = p[1792 + tid];
  red[tid] = y0 * y0 + y1 * y1; __syncthreads();
  for (int st = 128; st > 0; st >>= 1) { if (tid < st) red[tid] += red[tid + st]; __syncthreads(); }
  float scl2 = rsqrtf(red[0] * (1.f / 512.f) + EPS_F);
  kvc_b[(size_t)t * 512 + tid]       = f2b(y0 * scl2 * kvg[tid]);
  kvc_b[(size_t)t * 512 + 256 + tid] = f2b(y1 * scl2 * kvg[256 + tid]);
  if (tid < 32) {
    float a = p[2048 + tid], b = p[2080 + tid];
    float c = cosb[t * 32 + tid], sn = sinb[t * 32 + tid];
    kpe_b[(size_t)t * 64 + tid]      = f2b(a * c - b * sn);
    kpe_b[(size_t)t * 64 + 32 + tid] = f2b(a * sn + b * c);
  }
  __syncthreads();
  float z = (tid < 128) ? p[2112 + tid] : 0.f;
  red[tid] = z; __syncthreads();
  for (int st = 128; st > 0; st >>= 1) { if (tid < st) red[tid] += red[tid + st]; __syncthreads(); }
  float mean = red[0] * (1.f / 128.f);
  __syncthreads();
  float d = (tid < 128) ? (z - mean) : 0.f;
  red[tid] = d * d; __syncthreads();
  for (int st = 128; st > 0; st >>= 1) { if (tid < st) red[tid] += red[tid + st]; __syncthreads(); }
  float var = red[0] * (1.f / 128.f);
  if (tid < 128) buf[tid] = d * rsqrtf(var + EPS_F) * kng[tid] + knb[tid];
  __syncthreads();
  if (tid < 128) {
    float outv;
    if (tid < 32) {
      float c = cosb[t * 32 + tid], sn = sinb[t * 32 + tid];
      outv = buf[tid] * c - buf[tid + 32] * sn;
    } else if (tid < 64) {
      int j = tid - 32;
      float c = cosb[t * 32 + j], sn = sinb[t * 32 + j];
      outv = buf[j] * sn + buf[tid] * c;
    } else outv = buf[tid];
    ki_b[(size_t)t * 128 + tid] = f2b(outv);
  }
}

// ================= indexer scores via MFMA: 64x64 causal tiles =================
__global__ __launch_bounds__(256) void k_idx_mfma(
    const unsigned short* __restrict__ qi_b, int qpitch,
    const unsigned short* __restrict__ ki_b,
    const float* __restrict__ wb, int wstride,
    float* __restrict__ out) {
  int bid = blockIdx.x;
  int tb = (int)((sqrtf(8.f * bid + 1.f) - 1.f) * 0.5f);
  while ((tb + 1) * (tb + 2) / 2 <= bid) tb++;
  while (tb * (tb + 1) / 2 > bid) tb--;
  int sb = bid - tb * (tb + 1) / 2;
  int t0 = tb * 64, s0 = sb * 64;

  int tid = threadIdx.x, lane = tid & 63, w = tid >> 6;
  int wm = w >> 1, wn = w & 1;
  int l15 = lane & 15, quarter = lane >> 4;

  __shared__ unsigned short Ks[64 * 128];
  __shared__ unsigned short Qs[2][64 * 128];
  __shared__ float Ws[64][16];

  int srow_[4], scc_[4];
#pragma unroll
  for (int i = 0; i < 4; i++) {
    int row = w * 16 + i * 4 + (lane >> 4);
    srow_[i] = row;
    scc_[i] = (lane & 15) ^ (row & 7);
  }
#pragma unroll
  for (int i = 0; i < 4; i++) {
    gload16(ki_b + (size_t)(s0 + srow_[i]) * 128 + scc_[i] * 8, &Ks[(w * 16 + i * 4) * 128]);
    gload16(qi_b + (size_t)(t0 + srow_[i]) * qpitch + scc_[i] * 8, &Qs[0][(w * 16 + i * 4) * 128]);
  }
  for (int i = tid; i < 64 * 16; i += 256) Ws[i >> 4][i & 15] = wb[(size_t)(t0 + (i >> 4)) * wstride + (i & 15)];
  __syncthreads();

  bf16x8 bfr[2][4];
#pragma unroll
  for (int nf = 0; nf < 2; nf++) {
    int row = wn * 32 + nf * 16 + l15;
    int rx = (row & 7) << 3;
#pragma unroll
    for (int kc = 0; kc < 4; kc++)
      bfr[nf][kc] = *(const bf16x8*)(Ks + row * 128 + ((kc * 32 + quarter * 8) ^ rx));
  }

  f32x4 acc[2][2];
#pragma unroll
  for (int mf = 0; mf < 2; mf++)
#pragma unroll
    for (int nf = 0; nf < 2; nf++) acc[mf][nf] = (f32x4){0.f, 0.f, 0.f, 0.f};

  for (int h = 0; h < 16; h++) {
    int cur = h & 1;
    if (h < 15) {
#pragma unroll
      for (int i = 0; i < 4; i++)
        gload16(qi_b + (size_t)(t0 + srow_[i]) * qpitch + (h + 1) * 128 + scc_[i] * 8,
                &Qs[cur ^ 1][(w * 16 + i * 4) * 128]);
    }
    f32x4 acch[2][2];
#pragma unroll
    for (int mf = 0; mf < 2; mf++)
#pragma unroll
      for (int nf = 0; nf < 2; nf++) acch[mf][nf] = (f32x4){0.f, 0.f, 0.f, 0.f};

    __builtin_amdgcn_s_setprio(1);
#pragma unroll
    for (int mf = 0; mf < 2; mf++) {
      int row = wm * 32 + mf * 16 + l15;
      int rx = (row & 7) << 3;
      bf16x8 af[4];
#pragma unroll
      for (int kc = 0; kc < 4; kc++)
        af[kc] = *(const bf16x8*)(Qs[cur] + row * 128 + ((kc * 32 + quarter * 8) ^ rx));
#pragma unroll
      for (int nf = 0; nf < 2; nf++)
#pragma unroll
        for (int kc = 0; kc < 4; kc++)
          acch[mf][nf] = __builtin_amdgcn_mfma_f32_16x16x32_bf16(af[kc], bfr[nf][kc], acch[mf][nf], 0, 0, 0);
    }
    __builtin_amdgcn_s_setprio(0);
#pragma unroll
    for (int mf = 0; mf < 2; mf++) {
#pragma unroll
      for (int r = 0; r < 4; r++) {
        float wv = Ws[wm * 32 + mf * 16 + quarter * 4 + r][h];
#pragma unroll
        for (int nf = 0; nf < 2; nf++)
          acc[mf][nf][r] = fmaf(wv, fmaxf(acch[mf][nf][r], 0.f), acc[mf][nf][r]);
      }
    }
    __syncthreads();
  }
#pragma unroll
  for (int mf = 0; mf < 2; mf++)
#pragma unroll
    for (int nf = 0; nf < 2; nf++)
#pragma unroll
      for (int r = 0; r < 4; r++) {
        int t = t0 + wm * 32 + mf * 16 + quarter * 4 + r;
        int s = s0 + wn * 32 + nf * 16 + l15;
        out[(size_t)t * 2048 + s] = acc[mf][nf][r] * ISCALE_ID;
      }
}

// ================= per-row top-K -> bitmask (wave-scan radix select) =================
__global__ __launch_bounds__(256) void k_topk_mask(const float* __restrict__ idx_sc, u64* __restrict__ maskw) {
  int t = blockIdx.x;
  int tid = threadIdx.x;
  int n = t + 1;
  if (n <= TOPKC) {
    if (tid < 32) {
      int lo = tid * 64, hi = lo + 63;
      u64 wv;
      if (t >= hi) wv = ~0ULL;
      else if (t < lo) wv = 0ULL;
      else wv = (~0ULL) >> (63 - (t - lo));
      maskw[(size_t)t * 32 + tid] = wv;
    }
    return;
  }
  __shared__ unsigned int u[2048];
  __shared__ int hist[256];
  __shared__ int wtot[4];
  __shared__ u64 mw[32];
  __shared__ int sel_b, new_target;
  __shared__ int cnt[32];
  __shared__ u64 tmask[32];
  int lane = tid & 63, wid = tid >> 6;
  if (tid < 32) mw[tid] = 0ULL;
  const float* row = idx_sc + (size_t)t * 2048;
  for (int s = tid; s < n; s += 256) {
    unsigned int bb = __float_as_uint(row[s]);
    u[s] = (bb & 0x80000000u) ? ~bb : (bb | 0x80000000u);
  }
  unsigned int prefix = 0;
  int target = TOPKC;
  for (int shift = 24; shift >= 0; shift -= 8) {
    hist[tid] = 0;
    __syncthreads();
    unsigned int himask = (shift == 24) ? 0u : (0xFFFFFFFFu << (shift + 8));
    for (int s = tid; s < n; s += 256) {
      unsigned int uv = u[s];
      if ((uv & himask) == prefix) atomicAdd(&hist[(uv >> shift) & 0xFF], 1);
    }
    __syncthreads();
    int h = hist[tid];
    int sum = h;
#pragma unroll
    for (int off = 1; off < 64; off <<= 1) {
      int tv = __shfl_down(sum, off);
      if (lane + off < 64) sum += tv;
    }
    if (lane == 0) wtot[wid] = sum;
    __syncthreads();
    int scan = sum;
    for (int wI = wid + 1; wI < 4; wI++) scan += wtot[wI];
    if (scan >= target && scan - h < target) {
      sel_b = tid;
      new_target = target - (scan - h);
    }
    __syncthreads();
    prefix |= ((unsigned int)sel_b) << shift;
    target = new_target;
  }
#pragma unroll
  for (int i = 0; i < 8; i++) {
    int s = i * 256 + tid;
    bool in = (s < n);
    unsigned int uv = in ? u[s] : 0u;
    bool tie = in && (uv == prefix);
    u64 bal = __ballot(tie);
    if (lane == 0) { int c = i * 4 + wid; cnt[c] = __popcll(bal); tmask[c] = bal; }
    if (in && uv > prefix) atomicOr(&mw[s >> 6], 1ULL << (s & 63));
  }
  __syncthreads();
#pragma unroll
  for (int i = 0; i < 8; i++) {
    int s = i * 256 + tid;
    if (s >= n) continue;
    if (u[s] != prefix) continue;
    int c = i * 4 + wid;
    int base = 0;
    for (int c2 = 0; c2 < c; c2++) base += cnt[c2];
    int rank = base + __popcll(tmask[c] & ((1ULL << lane) - 1ULL));
    if (rank < target) atomicOr(&mw[s >> 6], 1ULL << (s & 63));
  }
  __syncthreads();
  if (tid < 32) maskw[(size_t)t * 32 + tid] = mw[tid];
}

// ================= MFMA flash attention: proven 93.4us structure (VGPR=128, NO setprio) =================
__global__ __launch_bounds__(256) void k_attn_mfma(
    const unsigned short* __restrict__ qb, int qpitch,
    const unsigned short* __restrict__ kvb_b,
    const unsigned short* __restrict__ kpe_b,
    const float* __restrict__ cosb, const float* __restrict__ sinb,
    const u64* __restrict__ maskw,
    unsigned short* __restrict__ attn_b) {
  int ybm = blockIdx.x;
  int h = blockIdx.y;
  int yb = (h < 8) ? ybm : (31 - ybm);
  int t0 = yb * 64;
  int tid = threadIdx.x;
  int lane = tid & 63, wq = tid >> 6;
  int quarter = lane >> 4, l15 = lane & 15;

  __shared__ unsigned short Kd[2][64 * 192];
  __shared__ unsigned short Vts[128 * 64];

  const unsigned short* kb_base[6];
  int kb_step[6];
#pragma unroll
  for (int i = 0; i < 6; i++) {
    int slot = (wq * 6 + i) * 1024 + lane * 16;
    int rowk = slot / 384;
    int coff = slot - rowk * 384;
    int cc = (coff ^ ((rowk & 7) << 4)) >> 4;
    if (cc < 16) { kb_base[i] = kvb_b + (size_t)rowk * 4096 + h * 256 + cc * 8; kb_step[i] = 4096; }
    else         { kb_base[i] = kpe_b + (size_t)rowk * 64 + (cc - 16) * 8;      kb_step[i] = 64; }
  }
  const int vdg = tid & 15, vsp = tid >> 4;
  const unsigned short* vbase = kvb_b + (size_t)(vsp * 4) * 4096 + h * 256 + 128 + vdg * 8;

  bf16x8 qf[6];
  {
    int t = t0 + wq * 16 + l15;
    const unsigned short* qp = qb + (size_t)t * qpitch + h * 192 + quarter * 8;
#pragma unroll
    for (int kc = 0; kc < 6; kc++) qf[kc] = *(const bf16x8*)(qp + kc * 32);
    const float* cp = cosb + t * 32 + quarter * 8;
    const float* sp = sinb + t * 32 + quarter * 8;
    float4 ca = *(const float4*)cp,  cb2 = *(const float4*)(cp + 4);
    float4 sa = *(const float4*)sp,  sb2 = *(const float4*)(sp + 4);
    float carr[8] = {ca.x, ca.y, ca.z, ca.w, cb2.x, cb2.y, cb2.z, cb2.w};
    float sarr[8] = {sa.x, sa.y, sa.z, sa.w, sb2.x, sb2.y, sb2.z, sb2.w};
#pragma unroll
    for (int j = 0; j < 8; j++) {
      float x1 = b2f((unsigned short)qf[4][j]);
      float x2 = b2f((unsigned short)qf[5][j]);
      qf[4][j] = (short)f2b(x1 * carr[j] - x2 * sarr[j]);
      qf[5][j] = (short)f2b(x1 * sarr[j] + x2 * carr[j]);
    }
  }

  f32x4 o[8];
#pragma unroll
  for (int df = 0; df < 8; df++) o[df] = (f32x4){0.f, 0.f, 0.f, 0.f};
  float mcol = -__builtin_inff(), lcol = 0.f;
  const u64* mrow = maskw + (size_t)(t0 + wq * 16 + l15) * 32;
  int nsb = yb + 1;

#pragma unroll
  for (int i = 0; i < 6; i++) gload16(kb_base[i], &Kd[0][(wq * 6 + i) * 512]);
  bf16x8 vr0 = *(const bf16x8*)(vbase);
  bf16x8 vr1 = *(const bf16x8*)(vbase + 4096);
  bf16x8 vr2 = *(const bf16x8*)(vbase + 8192);
  bf16x8 vr3 = *(const bf16x8*)(vbase + 12288);
  __syncthreads();
#pragma unroll
  for (int j = 0; j < 8; j++) {
    int d = vdg * 8 + j;
    uint2 w2;
    w2.x = (unsigned)(unsigned short)vr0[j] | (((unsigned)(unsigned short)vr1[j]) << 16);
    w2.y = (unsigned)(unsigned short)vr2[j] | (((unsigned)(unsigned short)vr3[j]) << 16);
    *(uint2*)((char*)Vts + d * 128 + ((vsp * 8) ^ (((d >> 2) & 7) << 4))) = w2;
  }

  for (int sb = 0; sb < nsb; sb++) {
    int cur = sb & 1;
    __syncthreads();
    bool pf = (sb + 1 < nsb);
    if (pf) {
      size_t sn = (size_t)(sb + 1) * 64;
#pragma unroll
      for (int i = 0; i < 6; i++)
        gload16(kb_base[i] + sn * kb_step[i], &Kd[cur ^ 1][(wq * 6 + i) * 512]);
      const unsigned short* vp = vbase + sn * 4096;
      vr0 = *(const bf16x8*)(vp);
      vr1 = *(const bf16x8*)(vp + 4096);
      vr2 = *(const bf16x8*)(vp + 8192);
      vr3 = *(const bf16x8*)(vp + 12288);
    }
    const unsigned short* Kc = Kd[cur];
    f32x4 sfT[4];
#pragma unroll
    for (int sc = 0; sc < 4; sc++) {
      f32x4 a = (f32x4){0.f, 0.f, 0.f, 0.f};
      int row = sc * 16 + l15;
      int rx = (row & 7) << 4;
#pragma unroll
      for (int kc = 0; kc < 6; kc++) {
        int byte = row * 384 + ((kc * 64 + quarter * 16) ^ rx);
        bf16x8 kf = *(const bf16x8*)((const char*)Kc + byte);
        a = __builtin_amdgcn_mfma_f32_16x16x32_bf16(kf, qf[kc], a, 0, 0, 0);
      }
      sfT[sc] = a;
    }
    u64 w64 = mrow[sb];
    float p[4][4];
#pragma unroll
    for (int sc = 0; sc < 4; sc++)
#pragma unroll
      for (int r = 0; r < 4; r++) {
        int sbit = sc * 16 + quarter * 4 + r;
        bool sel = (w64 >> sbit) & 1ULL;
        p[sc][r] = sel ? sfT[sc][r] * SCALE_ATTN : -__builtin_inff();
      }
    float v = p[0][0];
#pragma unroll
    for (int sc = 0; sc < 4; sc++)
#pragma unroll
      for (int r = 0; r < 4; r++) v = fmaxf(v, p[sc][r]);
    v = fmaxf(v, __shfl_xor(v, 16));
    v = fmaxf(v, __shfl_xor(v, 32));
    float mn = fmaxf(mcol, v);
    bool dead = (mn == -__builtin_inff());
    float scl = dead ? 1.f : __expf(mcol - mn);
#pragma unroll
    for (int sc = 0; sc < 4; sc++)
#pragma unroll
      for (int r = 0; r < 4; r++)
        p[sc][r] = dead ? 0.f : __expf(p[sc][r] - mn);
    mcol = dead ? mcol : mn;
    float rs = 0.f;
#pragma unroll
    for (int sc = 0; sc < 4; sc++)
#pragma unroll
      for (int r = 0; r < 4; r++) rs += p[sc][r];
    rs += __shfl_xor(rs, 16);
    rs += __shfl_xor(rs, 32);
    lcol = lcol * scl + rs;

    unsigned pk[4][2];
#pragma unroll
    for (int sc = 0; sc < 4; sc++)
#pragma unroll
      for (int rr = 0; rr < 2; rr++)
        pk[sc][rr] = (unsigned)f2b(p[sc][2 * rr]) | (((unsigned)f2b(p[sc][2 * rr + 1])) << 16);
    bf16x8 pa[2];
#pragma unroll
    for (int kc = 0; kc < 2; kc++) {
      union { unsigned d[4]; bf16x8 v; } pu;
#pragma unroll
      for (int jj = 0; jj < 4; jj++) {
        int src = ((quarter & 1) * 2 + (jj >> 1)) * 16 + l15;
        unsigned lo = (unsigned)__shfl((int)pk[kc * 2][jj & 1], src);
        unsigned hi = (unsigned)__shfl((int)pk[kc * 2 + 1][jj & 1], src);
        pu.d[jj] = (quarter < 2) ? lo : hi;
      }
      pa[kc] = pu.v;
    }
    float sclr[4];
#pragma unroll
    for (int r = 0; r < 4; r++) sclr[r] = __shfl(scl, quarter * 4 + r);
#pragma unroll
    for (int df = 0; df < 8; df++)
#pragma unroll
      for (int r = 0; r < 4; r++) o[df][r] *= sclr[r];
#pragma unroll
    for (int kc = 0; kc < 2; kc++)
#pragma unroll
      for (int df = 0; df < 8; df++) {
        int d = df * 16 + l15;
        int vbyte = d * 128 + ((kc * 64 + quarter * 16) ^ (((d >> 2) & 7) << 4));
        bf16x8 vf = *(const bf16x8*)((const char*)Vts + vbyte);
        o[df] = __builtin_amdgcn_mfma_f32_16x16x32_bf16(pa[kc], vf, o[df], 0, 0, 0);
      }
    __syncthreads();
    if (pf) {
#pragma unroll
      for (int j = 0; j < 8; j++) {
        int d = vdg * 8 + j;
        uint2 w2;
        w2.x = (unsigned)(unsigned short)vr0[j] | (((unsigned)(unsigned short)vr1[j]) << 16);
        w2.y = (unsigned)(unsigned short)vr2[j] | (((unsigned)(unsigned short)vr3[j]) << 16);
        *(uint2*)((char*)Vts + d * 128 + ((vsp * 8) ^ (((d >> 2) & 7) << 4))) = w2;
      }
    }
  }
  float inv = (lcol > 0.f) ? 1.f / lcol : 0.f;
  float invr[4];
#pragma unroll
  for (int r = 0; r < 4; r++) invr[r] = __shfl(inv, quarter * 4 + r);
#pragma unroll
  for (int r = 0; r < 4; r++) {
    int t = t0 + wq * 16 + quarter * 4 + r;
    unsigned short* op = attn_b + (size_t)t * 2048 + h * 128 + l15;
#pragma unroll
    for (int df = 0; df < 8; df++) op[df * 16] = f2b(o[df][r] * invr[r]);
  }
}

// ================= host launch =================
extern "C" void kernel_launch(void* const* d_in, const int* in_sizes, int n_in,
                              void* d_out, int out_size, void* d_ws, size_t ws_size,
                              hipStream_t stream) {
  const float* hs     = (const float*)d_in[0];
  const float* cosb   = (const float*)d_in[1];
  const float* sinb   = (const float*)d_in[2];
  const float* Wq_a   = (const float*)d_in[3];
  const float* q_a_g  = (const float*)d_in[4];
  const float* Wq_b   = (const float*)d_in[5];
  const float* Wkv_a  = (const float*)d_in[6];
  const float* kv_a_g = (const float*)d_in[7];
  const float* Wkv_b  = (const float*)d_in[8];
  const float* Wo     = (const float*)d_in[9];
  const float* Wq_idx = (const float*)d_in[10];
  const float* Wk_idx = (const float*)d_in[11];
  const float* Ww_idx = (const float*)d_in[12];
  const float* kn_g   = (const float*)d_in[13];
  const float* kn_b   = (const float*)d_in[14];
  float* out = (float*)d_out;

  char* base = (char*)d_ws;
  size_t off = 0;
  auto alloc = [&](size_t bytes) { void* p = base + off; off += (bytes + 255) & ~size_t(255); return p; };

  // fat1 f32 [2048][2304]: qa | kv | kpe | ki | wb(2240..2255); later attn_b (bf16)
  float* fat1 = (float*)alloc((size_t)S_ * 2304 * 4);
  unsigned short* attn_b = (unsigned short*)fat1;
  // idxs f32 [2048][2048]; WT1 (phase-1 weights) aliases it (dead by idx_mfma)
  float* idxs = (float*)alloc((size_t)S_ * 2048 * 4);
  unsigned short* WT1 = (unsigned short*)idxs;
  // fat2 bf16 [2048][5120]: qb | qi
  unsigned short* fat2 = (unsigned short*)alloc((size_t)S_ * 5120 * 2);
  u64*   maskw = (u64*)alloc((size_t)S_ * 32 * 8);
  unsigned short* hs_b  = (unsigned short*)alloc((size_t)S_ * 2048 * 2);
  unsigned short* qa_b  = (unsigned short*)alloc((size_t)S_ * 1536 * 2);
  unsigned short* kvc_b = (unsigned short*)alloc((size_t)S_ * 512 * 2);
  unsigned short* kpe_b = (unsigned short*)alloc((size_t)S_ * 64 * 2);
  unsigned short* kvb_b = (unsigned short*)alloc((size_t)S_ * 4096 * 2);
  unsigned short* ki_b  = (unsigned short*)alloc((size_t)S_ * 128 * 2);
  unsigned short* WT    = (unsigned short*)alloc((size_t)5120 * 1536 * 2);

  dim3 blk(256);

  // merged phase-1+2 weights + hs cast (one launch; p1 -> WT1 alias, p2 -> WT)
  k_tcast_p12<<<dim3(16384), blk, 0, stream>>>(Wq_a, Wkv_a, Wk_idx, Ww_idx, hs, hs_b, WT1,
                                               Wq_b, Wq_idx, WT);
  // fused hs-GEMM: N=2256 into fat1 (128x64 tiles, 576 blocks)
  k_gemm_n64<0><<<dim3(36, 16), blk, 0, stream>>>(hs_b, 2048, WT1, 2048, fat1, 2304, 2256);
  // fused norms
  k_norms<<<dim3(S_), blk, 0, stream>>>(fat1, 2304, q_a_g, kv_a_g, kn_g, kn_b, cosb, sinb,
                                        qa_b, kvc_b, kpe_b, ki_b);
  // fused qa-GEMM with qi-RoPE fused into the epilogue (MODE 2)
  k_gemm_bf16<2><<<dim3(40, 16), blk, 0, stream>>>(qa_b, 1536, WT, 1536, fat2, 5120, 5120, cosb, sinb);
  // phase-3 weights: [Wkv_b | Wo]^T -> WT
  k_tcast_p3<<<dim3(6144), blk, 0, stream>>>(Wkv_b, Wo, WT);
  // kvb = kv_c @ Wkv_b (128x64 tiles, 1024 blocks, bf16 out)
  k_gemm_n64<1><<<dim3(64, 16), blk, 0, stream>>>(kvc_b, 512, WT, 512, kvb_b, 4096, 4096);
  // indexer scores (triangular grid); wb from fat1 cols 2240.., stride 2304 (overwrites WT1 alias)
  k_idx_mfma<<<dim3(528), blk, 0, stream>>>(fat2 + 3072, 5120, ki_b, fat1 + 2240, 2304, idxs);
  // top-512 per row -> bitmask
  k_topk_mask<<<dim3(S_), blk, 0, stream>>>(idxs, maskw);
  // flash attention (proven structure, no setprio) -> attn_b (aliases fat1)
  k_attn_mfma<<<dim3(32, 16), blk, 0, stream>>>(fat2, 5120, kvb_b, kpe_b, cosb, sinb, maskw, attn_b);
  // out = attn @ Wo (128x64 tiles, 512 blocks; WT second slot)
  k_gemm_n64<0><<<dim3(32, 16), blk, 0, stream>>>(attn_b, 2048, WT + (size_t)4096 * 512, 2048, out, 2048, 2048);

  (void)in_sizes; (void)n_in; (void)out_size; (void)ws_size;
}